// Round 7
// baseline (872.826 us; speedup 1.0000x reference)
//
#include <hip/hip_runtime.h>
#include <hip/hip_bf16.h>
#include <hip/hip_cooperative_groups.h>

namespace cg = cooperative_groups;

// Problem constants (B=4, L=2048, D=512, M=1200, H=6)
// KEY INSIGHT: keyval is broadcast over L -> K rows identical -> softmax == 1/L exactly,
// mha == V[b] (per-batch constant), and leaky(slope=1) is identity so W2a@W2b folds.
// R7: single cooperative kernel, 6 phases separated by grid.sync() (kills 5 launch gaps +
// memset dispatch + per-stage fill/compute partition imbalance). Item functions identical
// to R6. Fallback to the R6 multi-kernel chain if cooperative launch is unavailable.

typedef __bf16 bf16x8 __attribute__((ext_vector_type(8)));
typedef float f32x4 __attribute__((ext_vector_type(4)));

constexpr size_t OUT3_N = 4ull * 2048 * 512;            // 4,194,304
constexpr size_t SM_N4  = (4ull * 6 * 2048 * 2048) / 4; // 25,165,824 f32x4
constexpr float  SMV    = 1.0f / 2048.0f;

// fill slice schedule (f32x4 units) — disjoint, covers SM exactly
constexpr size_t S1 = 0,        C1 = 5375000;
constexpr size_t S3 = 5375000,  C3 = 5687500;
constexpr size_t S4 = 11062500, C4 = 4750000;
constexpr size_t S5 = 15812500, C5 = 5187500;
constexpr size_t S6 = 21000000, C6 = 4165824;
static_assert(S6 + C6 == SM_N4, "fill slices must cover sm");

__device__ __forceinline__ void fill_slice(f32x4* __restrict__ p, size_t base, size_t cnt,
                                           int fb, int nfb){
    const f32x4 v = { SMV, SMV, SMV, SMV };
    const size_t stride = (size_t)nfb * 256;
    for (size_t j = (size_t)fb * 256 + threadIdx.x; j < cnt; j += stride)
        __builtin_nontemporal_store(v, p + base + j);
}

// ---------------- bf16 MFMA GEMM tile: C[64x64 at bm,bn] (+)= A[M,K] @ BT[N,K]^T over [k0beg,k0end)
// BK=64, 4 waves 2x2, global_load_lds width16, XOR-swizzled LDS (16B chunks: c8' = c8 ^ (r&7))
// MODE: 1 = atomicAdd fp32 (split-K), 2 = store bf16
template<int MODE, typename OutT>
__device__ void gemm_tile(const __bf16* __restrict__ A, const __bf16* __restrict__ BT,
                          OutT* __restrict__ C, int Ndim, int Kdim,
                          int bm, int bn, int k0beg, int k0end){
    __shared__ __bf16 As[64 * 64];
    __shared__ __bf16 Bs[64 * 64];
    const int tid = threadIdx.x, wave = tid >> 6, lane = tid & 63;
    const int r_st = wave * 8 + (lane >> 3);
    const int c8g  = (lane & 7) ^ (r_st & 7);
    const __bf16* Ag = A  + (size_t)(bm + r_st) * Kdim + c8g * 8;
    const __bf16* Bg = BT + (size_t)(bn + r_st) * Kdim + c8g * 8;
    const size_t rowskip = (size_t)32 * Kdim;
    const int wm = (wave >> 1) * 32, wn = (wave & 1) * 32;
    const int lm = lane & 15, lq = lane >> 4;
    f32x4 acc[2][2] = {};
    for (int k0 = k0beg; k0 < k0end; k0 += 64){
        __builtin_amdgcn_global_load_lds(
            (const __attribute__((address_space(1))) void*)(Ag + k0),
            (__attribute__((address_space(3))) void*)&As[wave * 512], 16, 0, 0);
        __builtin_amdgcn_global_load_lds(
            (const __attribute__((address_space(1))) void*)(Ag + k0 + rowskip),
            (__attribute__((address_space(3))) void*)&As[2048 + wave * 512], 16, 0, 0);
        __builtin_amdgcn_global_load_lds(
            (const __attribute__((address_space(1))) void*)(Bg + k0),
            (__attribute__((address_space(3))) void*)&Bs[wave * 512], 16, 0, 0);
        __builtin_amdgcn_global_load_lds(
            (const __attribute__((address_space(1))) void*)(Bg + k0 + rowskip),
            (__attribute__((address_space(3))) void*)&Bs[2048 + wave * 512], 16, 0, 0);
        __syncthreads();
        #pragma unroll
        for (int kb = 0; kb < 64; kb += 32){
            const int sw = (((kb >> 3) + lq) ^ (lm & 7)) << 3;
            bf16x8 a0 = *(const bf16x8*)&As[(wm + lm) * 64 + sw];
            bf16x8 a1 = *(const bf16x8*)&As[(wm + 16 + lm) * 64 + sw];
            bf16x8 b0 = *(const bf16x8*)&Bs[(wn + lm) * 64 + sw];
            bf16x8 b1 = *(const bf16x8*)&Bs[(wn + 16 + lm) * 64 + sw];
            acc[0][0] = __builtin_amdgcn_mfma_f32_16x16x32_bf16(a0, b0, acc[0][0], 0, 0, 0);
            acc[0][1] = __builtin_amdgcn_mfma_f32_16x16x32_bf16(a0, b1, acc[0][1], 0, 0, 0);
            acc[1][0] = __builtin_amdgcn_mfma_f32_16x16x32_bf16(a1, b0, acc[1][0], 0, 0, 0);
            acc[1][1] = __builtin_amdgcn_mfma_f32_16x16x32_bf16(a1, b1, acc[1][1], 0, 0, 0);
        }
        __syncthreads();
    }
    #pragma unroll
    for (int mi = 0; mi < 2; ++mi)
      #pragma unroll
      for (int ni = 0; ni < 2; ++ni)
        #pragma unroll
        for (int r = 0; r < 4; ++r){
            int row = bm + wm + mi * 16 + lq * 4 + r;   // C/D: row=(lane>>4)*4+reg
            int col = bn + wn + ni * 16 + lm;           //      col=lane&15
            if (MODE == 1) atomicAdd((float*)&C[(size_t)row * Ndim + col], acc[mi][ni][r]);
            else           C[(size_t)row * Ndim + col] = (OutT)acc[mi][ni][r];
        }
}

// ---------------- phase-item device functions (numerics identical to R6) ----------------

// P1 item: 0..1151 stack-cast [W2a;b2a;0]->A1; 1152..2175 tcast W2b->W2bT; 2176..2335 kv split-K
__device__ __forceinline__ void item_p1(int item, const float* __restrict__ W2a,
        const float* __restrict__ b2a, __bf16* __restrict__ A1,
        const float* __restrict__ W2b, __bf16* __restrict__ W2bT,
        const float* __restrict__ keyval, const float* __restrict__ Wkv,
        const float* __restrict__ bkv, float* __restrict__ V, float* __restrict__ shT){
    const int tid = threadIdx.x;
    if (item < 1152){
        int r = item >> 1;
        int c = (item & 1) * 1024 + tid * 4;
        float4 v;
        if (r < 512)       v = *(const float4*)(W2a + (size_t)r * 2048 + c);
        else if (r == 512) v = *(const float4*)(b2a + c);
        else               v = make_float4(0.f, 0.f, 0.f, 0.f);
        __bf16* o = A1 + (size_t)r * 2048 + c;
        o[0] = (__bf16)v.x; o[1] = (__bf16)v.y; o[2] = (__bf16)v.z; o[3] = (__bf16)v.w;
    } else if (item < 2176){
        int t = item - 1152;                   // 1024 tiles over W2b [2048][512]
        int c0 = (t & 15) * 32, r0 = (t >> 4) * 32;
        int tx = tid & 31, ty = tid >> 5;
        for (int i = ty; i < 32; i += 8)
            shT[i * 33 + tx] = W2b[(size_t)(r0 + i) * 512 + c0 + tx];
        __syncthreads();
        for (int i = ty; i < 32; i += 8)
            W2bT[(size_t)(c0 + i) * 2048 + r0 + tx] = (__bf16)shT[tx * 33 + i];
        __syncthreads();                       // LDS reuse across items
    } else {
        int i = item - 2176;                   // 160: b(4) x mc(5) x kc(8)
        int b = i & 3, mc = (i >> 2) % 5, kc = i / 20;
        int m = mc * 256 + tid;
        if (m < 1200){
            float acc = (kc == 0) ? bkv[1200 + m] : 0.f;
            const float* kvb = keyval + (size_t)b * 512;
            int d0 = kc * 64;
            #pragma unroll 8
            for (int d = d0; d < d0 + 64; ++d)
                acc += kvb[d] * Wkv[(size_t)d * 2400 + 1200 + m];
            atomicAdd(&V[b * 1200 + m], acc);
        }
    }
}

// P2 item: 0..287 fold GEMM split-K; 288..383 oc GEMV
__device__ __forceinline__ void item_p2(int item, const __bf16* __restrict__ A1,
        const __bf16* __restrict__ W2bT, float* __restrict__ Wf,
        const float* __restrict__ V, const float* __restrict__ Wff,
        const float* __restrict__ bff, float* __restrict__ oc){
    const int tid = threadIdx.x;
    if (item < 288){
        int tile = item % 72, kc = item / 72;
        gemm_tile<1>(A1, W2bT, Wf, 512, 2048, (tile % 9) * 64, (tile / 9) * 64,
                     kc * 512, (kc + 1) * 512);
    } else {
        int i = item - 288;                    // b(4) x jc(2) x kc(12), K=1200
        int b = i & 3, jc = (i >> 2) & 1, kc = i >> 3;
        int j = jc * 256 + tid;
        float acc = (kc == 0) ? bff[j] : 0.f;
        const float* vb = V + b * 1200;
        int m0 = kc * 100;
        #pragma unroll 5
        for (int m = m0; m < m0 + 100; ++m)
            acc += vb[m] * Wff[(size_t)m * 512 + j];
        atomicAdd(&oc[b * 512 + j], acc);
    }
}

// P3 item: 0..8191 ln1 rows; 8192..8447 tcast Wf->WfT
__device__ __forceinline__ void item_p3(int item, const float* __restrict__ q,
        const float* __restrict__ oc, const float* __restrict__ g1,
        const float* __restrict__ b1, __bf16* __restrict__ Xb,
        const float* __restrict__ Wf, __bf16* __restrict__ WfT, float* __restrict__ shT){
    const int t = threadIdx.x;
    if (item < 8192){
        const int b = item >> 11;
        const size_t base = (size_t)item * 512;
        float2 qv = *(const float2*)(q + base + 2 * t);
        float2 ov = *(const float2*)(oc + (size_t)b * 512 + 2 * t);
        float v0 = qv.x + ov.x, v1 = qv.y + ov.y;
        float s = v0 + v1, ss = v0 * v0 + v1 * v1;
        for (int off = 32; off; off >>= 1){ s += __shfl_down(s, off); ss += __shfl_down(ss, off); }
        int wv = t >> 6, ln = t & 63;
        if (ln == 0){ shT[wv] = s; shT[4 + wv] = ss; }
        __syncthreads();
        if (t == 0){
            float S  = shT[0] + shT[1] + shT[2] + shT[3];
            float SS = shT[4] + shT[5] + shT[6] + shT[7];
            float m = S * (1.0f / 512.0f);
            float var = SS * (1.0f / 512.0f) - m * m;
            shT[0] = m; shT[1] = rsqrtf(var + 1e-5f);
        }
        __syncthreads();
        float m = shT[0], r = shT[1];
        float2 gv = *(const float2*)(g1 + 2 * t);
        float2 bv = *(const float2*)(b1 + 2 * t);
        union { __bf16 h[2]; unsigned u; } pk;
        pk.h[0] = (__bf16)((v0 - m) * r * gv.x + bv.x);
        pk.h[1] = (__bf16)((v1 - m) * r * gv.y + bv.y);
        *(unsigned*)(Xb + base + 2 * t) = pk.u;
        __syncthreads();                       // LDS reuse across items
    } else {
        int tt = item - 8192;                  // 256 tiles over Wf [512][512]
        int c0 = (tt & 15) * 32, r0 = (tt >> 4) * 32;
        int tx = t & 31, ty = t >> 5;
        for (int i = ty; i < 32; i += 8)
            shT[i * 33 + tx] = Wf[(size_t)(r0 + i) * 512 + c0 + tx];
        __syncthreads();
        for (int i = ty; i < 32; i += 8)
            WfT[(size_t)(c0 + i) * 512 + r0 + tx] = (__bf16)shT[tx * 33 + i];
        __syncthreads();
    }
}

// P5 item: ln2 row
__device__ __forceinline__ void item_p5(int item, const __bf16* __restrict__ X,
        const __bf16* __restrict__ o2, const float* __restrict__ bfrow,
        const float* __restrict__ b2b, const float* __restrict__ g2,
        const float* __restrict__ b2, const float* __restrict__ keyval,
        float* __restrict__ out3, float* __restrict__ shT){
    const int t = threadIdx.x;
    const int b = item >> 11;
    const size_t base = (size_t)item * 512;
    union { unsigned u; __bf16 h[2]; } xv, yv;
    xv.u = *(const unsigned*)(X + base + 2 * t);
    yv.u = *(const unsigned*)(o2 + base + 2 * t);
    float f0 = bfrow[2 * t] + b2b[2 * t], f1 = bfrow[2 * t + 1] + b2b[2 * t + 1];
    float v0 = (float)xv.h[0] + (float)yv.h[0] + f0;
    float v1 = (float)xv.h[1] + (float)yv.h[1] + f1;
    float s = v0 + v1, ss = v0 * v0 + v1 * v1;
    for (int off = 32; off; off >>= 1){ s += __shfl_down(s, off); ss += __shfl_down(ss, off); }
    int wv = t >> 6, ln = t & 63;
    if (ln == 0){ shT[wv] = s; shT[4 + wv] = ss; }
    __syncthreads();
    if (t == 0){
        float S  = shT[0] + shT[1] + shT[2] + shT[3];
        float SS = shT[4] + shT[5] + shT[6] + shT[7];
        float m = S * (1.0f / 512.0f);
        float var = SS * (1.0f / 512.0f) - m * m;
        shT[0] = m; shT[1] = rsqrtf(var + 1e-5f);
    }
    __syncthreads();
    float m = shT[0], r = shT[1];
    float2 gv = *(const float2*)(g2 + 2 * t);
    float2 bv = *(const float2*)(b2 + 2 * t);
    float2 kv = *(const float2*)(keyval + (size_t)b * 512 + 2 * t);
    float y0 = (v0 - m) * r * gv.x + bv.x + kv.x;
    float y1 = (v1 - m) * r * gv.y + bv.y + kv.y;
    *(float2*)(out3 + base + 2 * t) = make_float2(y0, y1);
    __syncthreads();                           // LDS reuse across items
}

// ---------------- cooperative fused kernel ----------------
__global__ __launch_bounds__(256) void fused(const float* query, const float* keyval,
        const float* Wkv, const float* bkv, const float* Wff, const float* bff,
        const float* g1, const float* b1, const float* W2a, const float* b2a,
        const float* W2b, const float* b2b, const float* g2, const float* b2,
        float* out3, f32x4* smf, float* Wf, float* V, float* oc,
        __bf16* A1, __bf16* W2bT, __bf16* WfT, __bf16* X, __bf16* out2){
    __shared__ float shT[32 * 33];
    cg::grid_group g = cg::this_grid();
    const int nb = gridDim.x, bid = blockIdx.x;
    // P0: zero split-K accumulators (Wf,V,oc contiguous = 301,760 floats = 75,440 f32x4)
    for (size_t i = (size_t)bid * 256 + threadIdx.x; i < 75440; i += (size_t)nb * 256)
        ((f32x4*)Wf)[i] = (f32x4){0.f, 0.f, 0.f, 0.f};
    g.sync();
    // P1: prep + kv
    for (int item = bid; item < 2336; item += nb)
        item_p1(item, W2a, b2a, A1, W2b, W2bT, keyval, Wkv, bkv, V, shT);
    fill_slice(smf, S1, C1, bid, nb);
    g.sync();
    // P2: Wf fold + oc
    for (int item = bid; item < 384; item += nb)
        item_p2(item, A1, W2bT, Wf, V, Wff, bff, oc);
    fill_slice(smf, S3, C3, bid, nb);
    g.sync();
    // P3: ln1 + tcast Wf
    for (int item = bid; item < 8448; item += nb)
        item_p3(item, query, oc, g1, b1, X, Wf, WfT, shT);
    fill_slice(smf, S4, C4, bid, nb);
    g.sync();
    // P4: out2 = X @ Wfold (bf16 out)
    for (int item = bid; item < 1024; item += nb)
        gemm_tile<2>(X, WfT, out2, 512, 512, (item >> 3) * 64, (item & 7) * 64, 0, 512);
    fill_slice(smf, S5, C5, bid, nb);
    g.sync();
    // P5: ln2 (bfold row = Wf + 512*512)
    for (int item = bid; item < 8192; item += nb)
        item_p5(item, X, out2, Wf + 262144, b2b, g2, b2, keyval, out3, shT);
    fill_slice(smf, S6, C6, bid, nb);
}

// ---------------- fallback wrappers (R6 chain) ----------------
__global__ __launch_bounds__(256) void w1(const float* W2a, const float* b2a, __bf16* A1,
        const float* W2b, __bf16* W2bT, const float* keyval, const float* Wkv,
        const float* bkv, float* V, f32x4* smf){
    __shared__ float shT[32 * 33];
    const int bid = blockIdx.x;
    if (bid < 2336) item_p1(bid, W2a, b2a, A1, W2b, W2bT, keyval, Wkv, bkv, V, shT);
    else            fill_slice(smf, S1, C1, bid - 2336, 512);
}
__global__ __launch_bounds__(256) void w2(const __bf16* A1, const __bf16* W2bT, float* Wf,
        const float* V, const float* Wff, const float* bff, float* oc, f32x4* smf){
    const int bid = blockIdx.x;
    if (bid < 384) item_p2(bid, A1, W2bT, Wf, V, Wff, bff, oc);
    else           fill_slice(smf, S3, C3, bid - 384, 512);
}
__global__ __launch_bounds__(256) void w3(const float* q, const float* oc, const float* g1,
        const float* b1, __bf16* X, const float* Wf, __bf16* WfT, f32x4* smf){
    __shared__ float shT[32 * 33];
    const int bid = blockIdx.x;
    if (bid < 8448) item_p3(bid, q, oc, g1, b1, X, Wf, WfT, shT);
    else            fill_slice(smf, S4, C4, bid - 8448, 512);
}
__global__ __launch_bounds__(256) void w4(const __bf16* X, const __bf16* WfT,
        __bf16* out2, f32x4* smf){
    const int bid = blockIdx.x;
    if (bid < 1024) gemm_tile<2>(X, WfT, out2, 512, 512, (bid >> 3) * 64, (bid & 7) * 64, 0, 512);
    else            fill_slice(smf, S5, C5, bid - 1024, 512);
}
__global__ __launch_bounds__(256) void w5(const __bf16* X, const __bf16* out2,
        const float* bfrow, const float* b2b, const float* g2, const float* b2,
        const float* keyval, float* out3, f32x4* smf){
    __shared__ float shT[32 * 33];
    const int bid = blockIdx.x;
    if (bid < 8192) item_p5(bid, X, out2, bfrow, b2b, g2, b2, keyval, out3, shT);
    else            fill_slice(smf, S6, C6, bid - 8192, 512);
}

// ---------------- launch ----------------
extern "C" void kernel_launch(void* const* d_in, const int* in_sizes, int n_in,
                              void* d_out, int out_size, void* d_ws, size_t ws_size,
                              hipStream_t stream){
    const float* query  = (const float*)d_in[0];
    const float* keyval = (const float*)d_in[1];
    // d_in[2] Wq, d_in[3] bq: provably unused (softmax is uniform regardless of Q)
    const float* Wkv = (const float*)d_in[4];
    const float* bkv = (const float*)d_in[5];
    const float* Wff = (const float*)d_in[6];
    const float* bff = (const float*)d_in[7];
    const float* g1  = (const float*)d_in[8];
    const float* b1  = (const float*)d_in[9];
    const float* W2a = (const float*)d_in[10];
    const float* b2a = (const float*)d_in[11];
    const float* W2b = (const float*)d_in[12];
    const float* b2b = (const float*)d_in[13];
    const float* g2  = (const float*)d_in[14];
    const float* b2  = (const float*)d_in[15];

    float* out3 = (float*)d_out;
    f32x4* smf  = (f32x4*)(out3 + OUT3_N);

    // scratch (~24 MB): prefer d_ws; fall back to the sm region (filled last)
    char* base = (ws_size >= (64ull << 20)) ? (char*)d_ws : (char*)smf;
    float*  t_Wf   = (float*)base;                      // [576][512] fp32 (row 512 = b2a@W2b)
    float*  t_V    = t_Wf + 294912;                     // [4][1200]
    float*  t_oc   = t_V + 4800;                        // [4][512]
    __bf16* t_A1   = (__bf16*)(t_oc + 2048);            // [576][2048]
    __bf16* t_W2bT = t_A1 + 1179648;                    // [512][2048]
    __bf16* t_WfT  = t_W2bT + 1048576;                  // [512][512]
    __bf16* t_X    = t_WfT + 262144;                    // [8192][512]
    __bf16* t_out2 = t_X + 4194304;                     // [8192][512] bf16

    void* args[] = {
        (void*)&query, (void*)&keyval, (void*)&Wkv, (void*)&bkv, (void*)&Wff,
        (void*)&bff, (void*)&g1, (void*)&b1, (void*)&W2a, (void*)&b2a,
        (void*)&W2b, (void*)&b2b, (void*)&g2, (void*)&b2,
        (void*)&out3, (void*)&smf, (void*)&t_Wf, (void*)&t_V, (void*)&t_oc,
        (void*)&t_A1, (void*)&t_W2bT, (void*)&t_WfT, (void*)&t_X, (void*)&t_out2
    };
    hipError_t err = hipLaunchCooperativeKernel((const void*)fused, dim3(512), dim3(256),
                                                args, 0, stream);
    if (err != hipSuccess){
        // fallback: R6 multi-kernel chain (deterministic if coop is unsupported)
        (void)hipMemsetAsync(t_Wf, 0, 301760 * sizeof(float), stream);
        w1<<<2848, 256, 0, stream>>>(W2a, b2a, t_A1, W2b, t_W2bT, keyval, Wkv, bkv, t_V, smf);
        w2<<<896, 256, 0, stream>>>(t_A1, t_W2bT, t_Wf, t_V, Wff, bff, t_oc, smf);
        w3<<<8960, 256, 0, stream>>>(query, t_oc, g1, b1, t_X, t_Wf, t_WfT, smf);
        w4<<<1536, 256, 0, stream>>>(t_X, t_WfT, t_out2, smf);
        w5<<<8704, 256, 0, stream>>>(t_X, t_out2, t_Wf + 262144, b2b, g2, b2, keyval, out3, smf);
    }
}

// Round 8
// 488.489 us; speedup vs baseline: 1.7868x; 1.7868x over previous
//
#include <hip/hip_runtime.h>
#include <hip/hip_bf16.h>

// Problem constants (B=4, L=2048, D=512, M=1200, H=6)
// KEY INSIGHT: keyval is broadcast over L -> K rows identical -> softmax == 1/L exactly,
// mha == V[b] (per-batch constant), and leaky(slope=1) is identity so W2a@W2b folds.
// R8 = R6 chain (R7's cooperative fusion was latency-bound at 2 blocks/CU and reverted),
// with each stage's sm-fill slice distributed across ALL blocks of the stage grid
// (2048-8960 blocks instead of 512 dedicated fill workers -> store BW near ceiling).

typedef __bf16 bf16x8 __attribute__((ext_vector_type(8)));
typedef float f32x4 __attribute__((ext_vector_type(4)));

constexpr size_t OUT3_N = 4ull * 2048 * 512;            // 4,194,304
constexpr size_t SM_N4  = (4ull * 6 * 2048 * 2048) / 4; // 25,165,824 f32x4
constexpr float  SMV    = 1.0f / 2048.0f;

// fill slice schedule (f32x4 units) — disjoint, covers SM exactly
constexpr size_t S1 = 0,        C1 = 5375000;
constexpr size_t S3 = 5375000,  C3 = 5687500;
constexpr size_t S4 = 11062500, C4 = 4750000;
constexpr size_t S5 = 15812500, C5 = 5187500;
constexpr size_t S6 = 21000000, C6 = 4165824;
static_assert(S6 + C6 == SM_N4, "fill slices must cover sm");

__device__ __forceinline__ void fill_slice(f32x4* __restrict__ p, size_t base, size_t cnt,
                                           int fb, int nfb){
    const f32x4 v = { SMV, SMV, SMV, SMV };
    const size_t stride = (size_t)nfb * 256;
    for (size_t j = (size_t)fb * 256 + threadIdx.x; j < cnt; j += stride)
        __builtin_nontemporal_store(v, p + base + j);
}

// ---------------- bf16 MFMA GEMM tile: C[64x64 at bm,bn] (+)= A[M,K] @ BT[N,K]^T over [k0beg,k0end)
// BK=64, 4 waves 2x2, global_load_lds width16, XOR-swizzled LDS (16B chunks: c8' = c8 ^ (r&7))
// MODE: 1 = atomicAdd fp32 (split-K), 2 = store bf16
template<int MODE, typename OutT>
__device__ void gemm_tile(const __bf16* __restrict__ A, const __bf16* __restrict__ BT,
                          OutT* __restrict__ C, int Ndim, int Kdim,
                          int bm, int bn, int k0beg, int k0end){
    __shared__ __bf16 As[64 * 64];
    __shared__ __bf16 Bs[64 * 64];
    const int tid = threadIdx.x, wave = tid >> 6, lane = tid & 63;
    const int r_st = wave * 8 + (lane >> 3);
    const int c8g  = (lane & 7) ^ (r_st & 7);
    const __bf16* Ag = A  + (size_t)(bm + r_st) * Kdim + c8g * 8;
    const __bf16* Bg = BT + (size_t)(bn + r_st) * Kdim + c8g * 8;
    const size_t rowskip = (size_t)32 * Kdim;
    const int wm = (wave >> 1) * 32, wn = (wave & 1) * 32;
    const int lm = lane & 15, lq = lane >> 4;
    f32x4 acc[2][2] = {};
    for (int k0 = k0beg; k0 < k0end; k0 += 64){
        __builtin_amdgcn_global_load_lds(
            (const __attribute__((address_space(1))) void*)(Ag + k0),
            (__attribute__((address_space(3))) void*)&As[wave * 512], 16, 0, 0);
        __builtin_amdgcn_global_load_lds(
            (const __attribute__((address_space(1))) void*)(Ag + k0 + rowskip),
            (__attribute__((address_space(3))) void*)&As[2048 + wave * 512], 16, 0, 0);
        __builtin_amdgcn_global_load_lds(
            (const __attribute__((address_space(1))) void*)(Bg + k0),
            (__attribute__((address_space(3))) void*)&Bs[wave * 512], 16, 0, 0);
        __builtin_amdgcn_global_load_lds(
            (const __attribute__((address_space(1))) void*)(Bg + k0 + rowskip),
            (__attribute__((address_space(3))) void*)&Bs[2048 + wave * 512], 16, 0, 0);
        __syncthreads();
        #pragma unroll
        for (int kb = 0; kb < 64; kb += 32){
            const int sw = (((kb >> 3) + lq) ^ (lm & 7)) << 3;
            bf16x8 a0 = *(const bf16x8*)&As[(wm + lm) * 64 + sw];
            bf16x8 a1 = *(const bf16x8*)&As[(wm + 16 + lm) * 64 + sw];
            bf16x8 b0 = *(const bf16x8*)&Bs[(wn + lm) * 64 + sw];
            bf16x8 b1 = *(const bf16x8*)&Bs[(wn + 16 + lm) * 64 + sw];
            acc[0][0] = __builtin_amdgcn_mfma_f32_16x16x32_bf16(a0, b0, acc[0][0], 0, 0, 0);
            acc[0][1] = __builtin_amdgcn_mfma_f32_16x16x32_bf16(a0, b1, acc[0][1], 0, 0, 0);
            acc[1][0] = __builtin_amdgcn_mfma_f32_16x16x32_bf16(a1, b0, acc[1][0], 0, 0, 0);
            acc[1][1] = __builtin_amdgcn_mfma_f32_16x16x32_bf16(a1, b1, acc[1][1], 0, 0, 0);
        }
        __syncthreads();
    }
    #pragma unroll
    for (int mi = 0; mi < 2; ++mi)
      #pragma unroll
      for (int ni = 0; ni < 2; ++ni)
        #pragma unroll
        for (int r = 0; r < 4; ++r){
            int row = bm + wm + mi * 16 + lq * 4 + r;   // C/D: row=(lane>>4)*4+reg
            int col = bn + wn + ni * 16 + lm;           //      col=lane&15
            if (MODE == 1) atomicAdd((float*)&C[(size_t)row * Ndim + col], acc[mi][ni][r]);
            else           C[(size_t)row * Ndim + col] = (OutT)acc[mi][ni][r];
        }
}

// ---------------- k1: prep + kv split-K; ALL blocks then fill their C1 share ----------------
__global__ __launch_bounds__(256) void k1_prep_kv(const float* __restrict__ W2a,
        const float* __restrict__ b2a, __bf16* __restrict__ A1,
        const float* __restrict__ W2b, __bf16* __restrict__ W2bT,
        const float* __restrict__ keyval, const float* __restrict__ Wkv,
        const float* __restrict__ bkv, float* __restrict__ V, f32x4* __restrict__ smf){
    __shared__ float sh[32 * 33];
    const int bid = blockIdx.x, tid = threadIdx.x;
    if (bid < 1152){
        int r = bid >> 1;
        int c = (bid & 1) * 1024 + tid * 4;
        float4 v;
        if (r < 512)       v = *(const float4*)(W2a + (size_t)r * 2048 + c);
        else if (r == 512) v = *(const float4*)(b2a + c);
        else               v = make_float4(0.f, 0.f, 0.f, 0.f);
        __bf16* o = A1 + (size_t)r * 2048 + c;
        o[0] = (__bf16)v.x; o[1] = (__bf16)v.y; o[2] = (__bf16)v.z; o[3] = (__bf16)v.w;
    } else if (bid < 2176){
        int t = bid - 1152;                    // 1024 tiles over W2b [2048][512]
        int c0 = (t & 15) * 32, r0 = (t >> 4) * 32;
        int tx = tid & 31, ty = tid >> 5;
        for (int i = ty; i < 32; i += 8)
            sh[i * 33 + tx] = W2b[(size_t)(r0 + i) * 512 + c0 + tx];
        __syncthreads();
        for (int i = ty; i < 32; i += 8)
            W2bT[(size_t)(c0 + i) * 2048 + r0 + tx] = (__bf16)sh[tx * 33 + i];
    } else if (bid < 2336){
        int i = bid - 2176;                    // 160: b(4) x mc(5) x kc(8)
        int b = i & 3, mc = (i >> 2) % 5, kc = i / 20;
        int m = mc * 256 + tid;
        if (m < 1200){
            float acc = (kc == 0) ? bkv[1200 + m] : 0.f;
            const float* kvb = keyval + (size_t)b * 512;
            int d0 = kc * 64;
            #pragma unroll 8
            for (int d = d0; d < d0 + 64; ++d)
                acc += kvb[d] * Wkv[(size_t)d * 2400 + 1200 + m];
            atomicAdd(&V[b * 1200 + m], acc);
        }
    }
    fill_slice(smf, S1, C1, bid, 2848);
}

// ---------------- k3: fold GEMM split-K + oc GEMV; ALL blocks fill C3 share ----------------
__global__ __launch_bounds__(256) void k3_fold_oc(const __bf16* __restrict__ A1,
        const __bf16* __restrict__ W2bT, float* __restrict__ Wf,
        const float* __restrict__ V, const float* __restrict__ Wff,
        const float* __restrict__ bff, float* __restrict__ oc, f32x4* __restrict__ smf){
    const int bid = blockIdx.x, tid = threadIdx.x;
    if (bid < 288){                            // tile(9x8) x kc(4) over [576x512], K=2048
        int tile = bid % 72, kc = bid / 72;
        gemm_tile<1>(A1, W2bT, Wf, 512, 2048, (tile % 9) * 64, (tile / 9) * 64,
                     kc * 512, (kc + 1) * 512);
    } else if (bid < 384){                     // oc: b(4) x jc(2) x kc(12), K=1200
        int i = bid - 288;
        int b = i & 3, jc = (i >> 2) & 1, kc = i >> 3;
        int j = jc * 256 + tid;
        float acc = (kc == 0) ? bff[j] : 0.f;
        const float* vb = V + b * 1200;
        int m0 = kc * 100;
        #pragma unroll 5
        for (int m = m0; m < m0 + 100; ++m)
            acc += vb[m] * Wff[(size_t)m * 512 + j];
        atomicAdd(&oc[b * 512 + j], acc);
    }
    fill_slice(smf, S3, C3, bid, 2048);
}

// ---------------- k4: ln1 + tcast Wf->WfT; ALL blocks fill C4 share ----------------
__global__ __launch_bounds__(256) void k4_ln1_tcast(const float* __restrict__ q,
        const float* __restrict__ oc, const float* __restrict__ g1,
        const float* __restrict__ b1, __bf16* __restrict__ Xb,
        const float* __restrict__ Wf, __bf16* __restrict__ WfT, f32x4* __restrict__ smf){
    __shared__ float sh[32 * 33];
    const int bid = blockIdx.x, t = threadIdx.x;
    if (bid < 8192){
        const int b = bid >> 11;
        const size_t base = (size_t)bid * 512;
        float2 qv = *(const float2*)(q + base + 2 * t);
        float2 ov = *(const float2*)(oc + (size_t)b * 512 + 2 * t);
        float v0 = qv.x + ov.x, v1 = qv.y + ov.y;
        float s = v0 + v1, ss = v0 * v0 + v1 * v1;
        for (int off = 32; off; off >>= 1){ s += __shfl_down(s, off); ss += __shfl_down(ss, off); }
        int wv = t >> 6, ln = t & 63;
        if (ln == 0){ sh[wv] = s; sh[4 + wv] = ss; }
        __syncthreads();
        if (t == 0){
            float S  = sh[0] + sh[1] + sh[2] + sh[3];
            float SS = sh[4] + sh[5] + sh[6] + sh[7];
            float m = S * (1.0f / 512.0f);
            float var = SS * (1.0f / 512.0f) - m * m;
            sh[0] = m; sh[1] = rsqrtf(var + 1e-5f);
        }
        __syncthreads();
        float m = sh[0], r = sh[1];
        float2 gv = *(const float2*)(g1 + 2 * t);
        float2 bv = *(const float2*)(b1 + 2 * t);
        union { __bf16 h[2]; unsigned u; } pk;
        pk.h[0] = (__bf16)((v0 - m) * r * gv.x + bv.x);
        pk.h[1] = (__bf16)((v1 - m) * r * gv.y + bv.y);
        *(unsigned*)(Xb + base + 2 * t) = pk.u;
    } else if (bid < 8448){
        int tt = bid - 8192;                   // 256 tiles over Wf [512][512]
        int c0 = (tt & 15) * 32, r0 = (tt >> 4) * 32;
        int tx = t & 31, ty = t >> 5;
        for (int i = ty; i < 32; i += 8)
            sh[i * 33 + tx] = Wf[(size_t)(r0 + i) * 512 + c0 + tx];
        __syncthreads();
        for (int i = ty; i < 32; i += 8)
            WfT[(size_t)(c0 + i) * 512 + r0 + tx] = (__bf16)sh[tx * 33 + i];
    }
    fill_slice(smf, S4, C4, bid, 8960);
}

// ---------------- k5: main GEMM (out2 = X @ Wfold, bf16 out); ALL blocks fill C5 share ----------------
__global__ __launch_bounds__(256) void k5_gemm(const __bf16* __restrict__ X,
        const __bf16* __restrict__ WfT, __bf16* __restrict__ out2, f32x4* __restrict__ smf){
    const int bid = blockIdx.x;
    if (bid < 1024){                           // 128 x 8 tiles
        gemm_tile<2>(X, WfT, out2, 512, 512, (bid >> 3) * 64, (bid & 7) * 64, 0, 512);
    }
    fill_slice(smf, S5, C5, bid, 2048);
}

// ---------------- k6: ln2; ALL blocks fill C6 share ----------------
__global__ __launch_bounds__(256) void k6_ln2(const __bf16* __restrict__ X,
        const __bf16* __restrict__ o2, const float* __restrict__ bfrow,
        const float* __restrict__ b2b, const float* __restrict__ g2,
        const float* __restrict__ b2, const float* __restrict__ keyval,
        float* __restrict__ out3, f32x4* __restrict__ smf){
    __shared__ float sh[8];
    const int bid = blockIdx.x, t = threadIdx.x;
    if (bid < 8192){
        const int b = bid >> 11;
        const size_t base = (size_t)bid * 512;
        union { unsigned u; __bf16 h[2]; } xv, yv;
        xv.u = *(const unsigned*)(X + base + 2 * t);
        yv.u = *(const unsigned*)(o2 + base + 2 * t);
        float f0 = bfrow[2 * t] + b2b[2 * t], f1 = bfrow[2 * t + 1] + b2b[2 * t + 1];
        float v0 = (float)xv.h[0] + (float)yv.h[0] + f0;
        float v1 = (float)xv.h[1] + (float)yv.h[1] + f1;
        float s = v0 + v1, ss = v0 * v0 + v1 * v1;
        for (int off = 32; off; off >>= 1){ s += __shfl_down(s, off); ss += __shfl_down(ss, off); }
        int wv = t >> 6, ln = t & 63;
        if (ln == 0){ sh[wv] = s; sh[4 + wv] = ss; }
        __syncthreads();
        if (t == 0){
            float S  = sh[0] + sh[1] + sh[2] + sh[3];
            float SS = sh[4] + sh[5] + sh[6] + sh[7];
            float m = S * (1.0f / 512.0f);
            float var = SS * (1.0f / 512.0f) - m * m;
            sh[0] = m; sh[1] = rsqrtf(var + 1e-5f);
        }
        __syncthreads();
        float m = sh[0], r = sh[1];
        float2 gv = *(const float2*)(g2 + 2 * t);
        float2 bv = *(const float2*)(b2 + 2 * t);
        float2 kv = *(const float2*)(keyval + (size_t)b * 512 + 2 * t);
        float y0 = (v0 - m) * r * gv.x + bv.x + kv.x;
        float y1 = (v1 - m) * r * gv.y + bv.y + kv.y;
        *(float2*)(out3 + base + 2 * t) = make_float2(y0, y1);
    }
    fill_slice(smf, S6, C6, bid, 8704);
}

// ---------------- launch ----------------
extern "C" void kernel_launch(void* const* d_in, const int* in_sizes, int n_in,
                              void* d_out, int out_size, void* d_ws, size_t ws_size,
                              hipStream_t stream){
    const float* query  = (const float*)d_in[0];
    const float* keyval = (const float*)d_in[1];
    // d_in[2] Wq, d_in[3] bq: provably unused (softmax is uniform regardless of Q)
    const float* Wkv = (const float*)d_in[4];
    const float* bkv = (const float*)d_in[5];
    const float* Wff = (const float*)d_in[6];
    const float* bff = (const float*)d_in[7];
    const float* g1  = (const float*)d_in[8];
    const float* b1  = (const float*)d_in[9];
    const float* W2a = (const float*)d_in[10];
    const float* b2a = (const float*)d_in[11];
    const float* W2b = (const float*)d_in[12];
    const float* b2b = (const float*)d_in[13];
    const float* g2  = (const float*)d_in[14];
    const float* b2  = (const float*)d_in[15];

    float* out3 = (float*)d_out;
    f32x4* smf  = (f32x4*)(out3 + OUT3_N);

    // scratch (~24 MB): prefer d_ws; fall back to the sm region (filled last)
    char* base = (ws_size >= (64ull << 20)) ? (char*)d_ws : (char*)smf;
    float*  t_Wf   = (float*)base;                      // [576][512] fp32 (row 512 = b2a@W2b)
    float*  t_V    = t_Wf + 294912;                     // [4][1200]
    float*  t_oc   = t_V + 4800;                        // [4][512]
    __bf16* t_A1   = (__bf16*)(t_oc + 2048);            // [576][2048]
    __bf16* t_W2bT = t_A1 + 1179648;                    // [512][2048]
    __bf16* t_WfT  = t_W2bT + 1048576;                  // [512][512]
    __bf16* t_X    = t_WfT + 262144;                    // [8192][512]
    __bf16* t_out2 = t_X + 4194304;                     // [8192][512] bf16

    // zero split-K accumulators (Wf, V, oc contiguous = 301,760 floats)
    (void)hipMemsetAsync(t_Wf, 0, 301760 * sizeof(float), stream);
    k1_prep_kv<<<2848, 256, 0, stream>>>(W2a, b2a, t_A1, W2b, t_W2bT,
                                         keyval, Wkv, bkv, t_V, smf);
    k3_fold_oc<<<2048, 256, 0, stream>>>(t_A1, t_W2bT, t_Wf, t_V, Wff, bff, t_oc, smf);
    k4_ln1_tcast<<<8960, 256, 0, stream>>>(query, t_oc, g1, b1, t_X, t_Wf, t_WfT, smf);
    k5_gemm<<<2048, 256, 0, stream>>>(t_X, t_WfT, t_out2, smf);
    // bfold row = row 512 of Wf (starts at 512*512)
    k6_ln2<<<8704, 256, 0, stream>>>(t_X, t_out2, t_Wf + 262144, b2b, g2, b2,
                                     keyval, out3, smf);
}